// Round 2
// baseline (319.068 us; speedup 1.0000x reference)
//
#include <hip/hip_runtime.h>
#include <hip/hip_bf16.h>
#include <math.h>

typedef __bf16 bf16x8 __attribute__((ext_vector_type(8)));
typedef float f32x4 __attribute__((ext_vector_type(4)));

#define GAS __attribute__((address_space(1)))
#define LAS __attribute__((address_space(3)))

static __device__ __forceinline__ void load16(const void* g, void* l) {
    __builtin_amdgcn_global_load_lds((const GAS void*)g, (LAS void*)l, 16, 0, 0);
}

struct __align__(8) bh4 { __hip_bfloat16 x, y, z, w; };

// ---------- fused LayerNorm (blocks 0..nln-1) + weight cast (blocks nln..) ----------
__global__ __launch_bounds__(256) void pre_kernel(
        const float* __restrict__ x, const float* __restrict__ gamma,
        const float* __restrict__ beta, const float* __restrict__ w1,
        const float* __restrict__ w2, __hip_bfloat16* __restrict__ hn,
        __hip_bfloat16* __restrict__ w1b, __hip_bfloat16* __restrict__ w2b, int nln) {
    if ((int)blockIdx.x >= nln) {   // weight cast: 1024 blocks x 256 thr x 4 elems
        const int i = (blockIdx.x - nln) * 256 + threadIdx.x;
        float4 a = ((const float4*)w1)[i];
        float4 b = ((const float4*)w2)[i];
        bh4 r1, r2;
        r1.x = __float2bfloat16(a.x); r1.y = __float2bfloat16(a.y);
        r1.z = __float2bfloat16(a.z); r1.w = __float2bfloat16(a.w);
        r2.x = __float2bfloat16(b.x); r2.y = __float2bfloat16(b.y);
        r2.z = __float2bfloat16(b.z); r2.w = __float2bfloat16(b.w);
        ((bh4*)w1b)[i] = r1;
        ((bh4*)w2b)[i] = r2;
        return;
    }
    const int row  = (blockIdx.x << 2) + (threadIdx.x >> 6);
    const int lane = threadIdx.x & 63;
    const float4* px = (const float4*)(x + (size_t)row * 1024);
    float4 v[4];
    float s = 0.f;
#pragma unroll
    for (int i = 0; i < 4; ++i) {
        v[i] = px[lane + (i << 6)];
        s += v[i].x + v[i].y + v[i].z + v[i].w;
    }
#pragma unroll
    for (int o = 32; o; o >>= 1) s += __shfl_xor(s, o, 64);
    const float mu = s * (1.0f / 1024.0f);
    float vs = 0.f;
#pragma unroll
    for (int i = 0; i < 4; ++i) {
        float a = v[i].x - mu, b = v[i].y - mu, c = v[i].z - mu, d = v[i].w - mu;
        vs += a * a + b * b + c * c + d * d;
    }
#pragma unroll
    for (int o = 32; o; o >>= 1) vs += __shfl_xor(vs, o, 64);
    const float rs = rsqrtf(vs * (1.0f / 1024.0f) + 1e-5f);
    const float4* pg = (const float4*)gamma;
    const float4* pb = (const float4*)beta;
    bh4* po = (bh4*)(hn + (size_t)row * 1024);
#pragma unroll
    for (int i = 0; i < 4; ++i) {
        const int idx = lane + (i << 6);
        float4 g = pg[idx], bb = pb[idx];
        bh4 r;
        r.x = __float2bfloat16((v[i].x - mu) * rs * g.x + bb.x);
        r.y = __float2bfloat16((v[i].y - mu) * rs * g.y + bb.y);
        r.z = __float2bfloat16((v[i].z - mu) * rs * g.z + bb.z);
        r.w = __float2bfloat16((v[i].w - mu) * rs * g.w + bb.w);
        po[idx] = r;
    }
}

// ---------------- GEMM (B^T weights), 128x128 tile, BK=64, MFMA 16x16x32 bf16 ----
// LDS is kept in MFMA-FRAGMENT ORDER (not row-major):
//   sA chunk u = rg*2+c  (rg=row-group of 16, c=k-chunk of 32) holds, at lane*16,
//       A[bm + rg*16 + (l&15)][kt + c*32 + (l>>4)*8 .. +8]
//   sB chunk u = (cg*4+j)*2+c holds B[bn + cg*64 + (l&15)*4 + j][same k]
//   => every ds_read_b128 is a contiguous 1KB wave read: ZERO bank conflicts.
//   B col mapping col = f*4+j gives each lane 4 CONTIGUOUS output columns.
// EPI==0: out_bf16 = gelu(A*B^T + bias); EPI==1: out_f32 = A*B^T + bias + resid
template <int EPI>
__global__ __launch_bounds__(256, 4) void gemm_kernel(
        const __hip_bfloat16* __restrict__ A,
        const __hip_bfloat16* __restrict__ B,
        const float* __restrict__ bias,
        const float* __restrict__ resid,
        __hip_bfloat16* __restrict__ outb,
        float* __restrict__ outf) {
    constexpr int K = 1024, N = 1024;
    __shared__ __align__(16) char sA[16384];
    __shared__ __align__(16) char sB[16384];

    const int tid  = threadIdx.x;
    const int lane = tid & 63;
    const int w    = tid >> 6;
    const int wm   = (w >> 1) * 64;   // wave row base in tile
    const int wn   = (w & 1) * 64;    // wave col base in tile
    const int bm   = blockIdx.x * 128;
    const int bn   = blockIdx.y * 128;

    const int f = lane & 15;
    const int h = lane >> 4;

    // staging sources: thread stages chunk u = q*4 + w  (q = 0..3) for A and B
    const __hip_bfloat16* gA[4];
    const __hip_bfloat16* gB[4];
#pragma unroll
    for (int q = 0; q < 4; ++q) {
        const int u  = q * 4 + w;
        const int rg = u >> 1, c = u & 1;           // A decode
        gA[q] = A + (size_t)(bm + rg * 16 + f) * K + c * 32 + h * 8;
        const int cg = u >> 3, j = (u >> 1) & 3;    // B decode (same c)
        gB[q] = B + (size_t)(bn + cg * 64 + f * 4 + j) * K + c * 32 + h * 8;
    }
    char* lA = sA + tid * 16;   // == chunk (q*4+w)*1024 + lane*16 when += q*4096
    char* lB = sB + tid * 16;

    f32x4 acc[4][4] = {};

    for (int kt = 0; kt < K; kt += 64) {
#pragma unroll
        for (int q = 0; q < 4; ++q) {
            load16(gA[q] + kt, lA + q * 4096);
            load16(gB[q] + kt, lB + q * 4096);
        }
        __syncthreads();                       // staged tiles visible
#pragma unroll
        for (int c = 0; c < 2; ++c) {
            bf16x8 af[4], bf[4];
#pragma unroll
            for (int i = 0; i < 4; ++i)
                af[i] = *(const bf16x8*)(sA + ((((wm >> 4) + i) * 2 + c) << 10) + lane * 16);
#pragma unroll
            for (int j = 0; j < 4; ++j)
                bf[j] = *(const bf16x8*)(sB + ((((wn >> 4) + j) * 2 + c) << 10) + lane * 16);
#pragma unroll
            for (int i = 0; i < 4; ++i)
#pragma unroll
                for (int j = 0; j < 4; ++j)
                    acc[i][j] = __builtin_amdgcn_mfma_f32_16x16x32_bf16(af[i], bf[j], acc[i][j], 0, 0, 0);
        }
        __syncthreads();                       // reads done before next stage
    }

    // epilogue: lane owns rows wm+i*16+h*4+r, 4 contiguous cols bn+wn+f*4..+3
    const float4 bias4 = *(const float4*)(bias + bn + wn + f * 4);
    const int colb = bn + wn + f * 4;
#pragma unroll
    for (int i = 0; i < 4; ++i) {
#pragma unroll
        for (int r = 0; r < 4; ++r) {
            const size_t grow = (size_t)(bm + wm + i * 16 + h * 4 + r);
            float v0 = acc[i][0][r] + bias4.x;
            float v1 = acc[i][1][r] + bias4.y;
            float v2 = acc[i][2][r] + bias4.z;
            float v3 = acc[i][3][r] + bias4.w;
            if (EPI == 0) {
                bh4 o;
                o.x = __float2bfloat16(0.5f * v0 * (1.0f + erff(v0 * 0.70710678118654752f)));
                o.y = __float2bfloat16(0.5f * v1 * (1.0f + erff(v1 * 0.70710678118654752f)));
                o.z = __float2bfloat16(0.5f * v2 * (1.0f + erff(v2 * 0.70710678118654752f)));
                o.w = __float2bfloat16(0.5f * v3 * (1.0f + erff(v3 * 0.70710678118654752f)));
                *(bh4*)(outb + grow * N + colb) = o;
            } else {
                const float4 rs = *(const float4*)(resid + grow * N + colb);
                float4 o = {v0 + rs.x, v1 + rs.y, v2 + rs.z, v3 + rs.w};
                *(float4*)(outf + grow * N + colb) = o;
            }
        }
    }
}

extern "C" void kernel_launch(void* const* d_in, const int* in_sizes, int n_in,
                              void* d_out, int out_size, void* d_ws, size_t ws_size,
                              hipStream_t stream) {
    const float* x     = (const float*)d_in[0];
    const float* gamma = (const float*)d_in[1];
    const float* beta  = (const float*)d_in[2];
    const float* w1    = (const float*)d_in[3];
    const float* b1    = (const float*)d_in[4];
    const float* w2    = (const float*)d_in[5];
    const float* b2    = (const float*)d_in[6];
    float* out = (float*)d_out;

    const int M = in_sizes[0] / 1024;   // 16384

    char* ws = (char*)d_ws;
    __hip_bfloat16* hn  = (__hip_bfloat16*)ws;                          // 32 MiB
    __hip_bfloat16* h1  = (__hip_bfloat16*)(ws + (size_t)M * 2048);     // 32 MiB
    __hip_bfloat16* w1b = (__hip_bfloat16*)(ws + (size_t)M * 4096);     // 2 MiB
    __hip_bfloat16* w2b = (__hip_bfloat16*)(ws + (size_t)M * 4096 + 2097152);

    const int nln = M / 4;   // 4096 LN blocks + 1024 cvt blocks
    pre_kernel<<<nln + 1024, 256, 0, stream>>>(x, gamma, beta, w1, w2, hn, w1b, w2b, nln);
    // grid x = bm so id%8 = bm%8: all 8 bn-blocks of one bm land on one XCD (A-tile L2 reuse)
    gemm_kernel<0><<<dim3(M / 128, 8), 256, 0, stream>>>(hn, w1b, b1, nullptr, h1, nullptr);
    gemm_kernel<1><<<dim3(M / 128, 8), 256, 0, stream>>>(h1, w2b, b2, x, nullptr, out);
}

// Round 3
// 227.256 us; speedup vs baseline: 1.4040x; 1.4040x over previous
//
#include <hip/hip_runtime.h>
#include <hip/hip_bf16.h>
#include <math.h>

typedef __bf16 bf16x8 __attribute__((ext_vector_type(8)));
typedef float f32x4 __attribute__((ext_vector_type(4)));

#define GAS __attribute__((address_space(1)))
#define LAS __attribute__((address_space(3)))

static __device__ __forceinline__ void load16(const void* g, void* l) {
    __builtin_amdgcn_global_load_lds((const GAS void*)g, (LAS void*)l, 16, 0, 0);
}

struct __align__(8) bh4 { __hip_bfloat16 x, y, z, w; };

// ---------- fused LayerNorm (blocks 0..nln-1) + weight cast (blocks nln..) ----------
__global__ __launch_bounds__(256) void pre_kernel(
        const float* __restrict__ x, const float* __restrict__ gamma,
        const float* __restrict__ beta, const float* __restrict__ w1,
        const float* __restrict__ w2, __hip_bfloat16* __restrict__ hn,
        __hip_bfloat16* __restrict__ w1b, __hip_bfloat16* __restrict__ w2b, int nln) {
    if ((int)blockIdx.x >= nln) {   // weight cast: 1024 blocks x 256 thr x 4 elems
        const int i = (blockIdx.x - nln) * 256 + threadIdx.x;
        float4 a = ((const float4*)w1)[i];
        float4 b = ((const float4*)w2)[i];
        bh4 r1, r2;
        r1.x = __float2bfloat16(a.x); r1.y = __float2bfloat16(a.y);
        r1.z = __float2bfloat16(a.z); r1.w = __float2bfloat16(a.w);
        r2.x = __float2bfloat16(b.x); r2.y = __float2bfloat16(b.y);
        r2.z = __float2bfloat16(b.z); r2.w = __float2bfloat16(b.w);
        ((bh4*)w1b)[i] = r1;
        ((bh4*)w2b)[i] = r2;
        return;
    }
    const int row  = (blockIdx.x << 2) + (threadIdx.x >> 6);
    const int lane = threadIdx.x & 63;
    const float4* px = (const float4*)(x + (size_t)row * 1024);
    float4 v[4];
    float s = 0.f;
#pragma unroll
    for (int i = 0; i < 4; ++i) {
        v[i] = px[lane + (i << 6)];
        s += v[i].x + v[i].y + v[i].z + v[i].w;
    }
#pragma unroll
    for (int o = 32; o; o >>= 1) s += __shfl_xor(s, o, 64);
    const float mu = s * (1.0f / 1024.0f);
    float vs = 0.f;
#pragma unroll
    for (int i = 0; i < 4; ++i) {
        float a = v[i].x - mu, b = v[i].y - mu, c = v[i].z - mu, d = v[i].w - mu;
        vs += a * a + b * b + c * c + d * d;
    }
#pragma unroll
    for (int o = 32; o; o >>= 1) vs += __shfl_xor(vs, o, 64);
    const float rs = rsqrtf(vs * (1.0f / 1024.0f) + 1e-5f);
    const float4* pg = (const float4*)gamma;
    const float4* pb = (const float4*)beta;
    bh4* po = (bh4*)(hn + (size_t)row * 1024);
#pragma unroll
    for (int i = 0; i < 4; ++i) {
        const int idx = lane + (i << 6);
        float4 g = pg[idx], bb = pb[idx];
        bh4 r;
        r.x = __float2bfloat16((v[i].x - mu) * rs * g.x + bb.x);
        r.y = __float2bfloat16((v[i].y - mu) * rs * g.y + bb.y);
        r.z = __float2bfloat16((v[i].z - mu) * rs * g.z + bb.z);
        r.w = __float2bfloat16((v[i].w - mu) * rs * g.w + bb.w);
        po[idx] = r;
    }
}

// ---------------- GEMM (B^T weights), 128x128 tile, BK=64, MFMA 16x16x32 bf16 ----
// LDS: row-major [128 rows x 64 cols bf16] = 128 B/row = 8 chunks of 16 B, with
// XOR chunk swizzle to kill bank conflicts while keeping global_load_lds sources
// contiguous per row (8 lanes cover one 128-B row segment, permuted within it):
//   sA: physical chunk p = logical ^ (row & 7)       (frag reads stride 16 rows)
//   sB: physical chunk p = logical ^ ((row>>2) & 7)  (frag reads stride 4 rows)
// B fragment j, lane f reads LDS row wn+4f+j -> lane's 4 output cols contiguous.
// Fragment-read banks: p = (c*4+h) ^ (f&7) spreads 16 lanes over 8 chunk slots
// -> 2 lanes/bank-group = free (m136).
// EPI==0: out_bf16 = gelu(A*B^T + bias); EPI==1: out_f32 = A*B^T + bias + resid
template <int EPI>
__global__ __launch_bounds__(256) void gemm_kernel(
        const __hip_bfloat16* __restrict__ A,
        const __hip_bfloat16* __restrict__ B,
        const float* __restrict__ bias,
        const float* __restrict__ resid,
        __hip_bfloat16* __restrict__ outb,
        float* __restrict__ outf) {
    constexpr int K = 1024, N = 1024;
    __shared__ __align__(16) char sA[16384];
    __shared__ __align__(16) char sB[16384];

    const int tid  = threadIdx.x;
    const int lane = tid & 63;
    const int w    = tid >> 6;
    const int wm   = (w >> 1) * 64;   // wave row base in tile
    const int wn   = (w & 1) * 64;    // wave col base in tile
    const int bm   = blockIdx.x * 128;
    const int bn   = blockIdx.y * 128;

    const int f = lane & 15;
    const int h = lane >> 4;

    // staging sources (identity rows, column chunk permuted per swizzle)
    const int srow = tid >> 3;                       // row within 32-row group
    const int lA_chunk = (tid & 7) ^ (srow & 7);     // sA swizzle key = row&7
    const int lB_chunk = (tid & 7) ^ ((tid >> 5) & 7); // sB key = (row>>2)&7
    const __hip_bfloat16* sa = A + (size_t)(bm + srow) * K + lA_chunk * 8;
    const __hip_bfloat16* sb = B + (size_t)(bn + srow) * K + lB_chunk * 8;
    char* dA = sA + tid * 16;   // dst forced: base + lane*16; inst q adds q*4096
    char* dB = sB + tid * 16;

    // fragment read bases
    const int pxk = (f & 7) * 16;                 // xor key in bytes
    const int px0 = (h * 16) ^ pxk;               // c=0: p=(h)^(f&7)
    const int px1 = ((4 + h) * 16) ^ pxk;         // c=1: p=(4+h)^(f&7)
    const char* aBase = sA + (wm + f) * 128;
    const char* bBase = sB + (wn + 4 * f) * 128;

    f32x4 acc[4][4] = {};

    for (int kt = 0; kt < K; kt += 64) {
#pragma unroll
        for (int q = 0; q < 4; ++q) {
            load16(sa + kt + q * 32 * K, dA + q * 4096);
            load16(sb + kt + q * 32 * K, dB + q * 4096);
        }
        __syncthreads();                       // staged tiles visible
#pragma unroll
        for (int c = 0; c < 2; ++c) {
            const int px = c ? px1 : px0;
            bf16x8 af[4], bf[4];
#pragma unroll
            for (int i = 0; i < 4; ++i)
                af[i] = *(const bf16x8*)(aBase + i * 2048 + px);
#pragma unroll
            for (int j = 0; j < 4; ++j)
                bf[j] = *(const bf16x8*)(bBase + j * 128 + px);
#pragma unroll
            for (int i = 0; i < 4; ++i)
#pragma unroll
                for (int j = 0; j < 4; ++j)
                    acc[i][j] = __builtin_amdgcn_mfma_f32_16x16x32_bf16(af[i], bf[j], acc[i][j], 0, 0, 0);
        }
        __syncthreads();                       // reads done before next stage
    }

    // epilogue: lane owns rows wm+i*16+h*4+r, 4 contiguous cols bn+wn+4f..+3
    const int colb = bn + wn + f * 4;
    const float4 bias4 = *(const float4*)(bias + colb);
#pragma unroll
    for (int i = 0; i < 4; ++i) {
#pragma unroll
        for (int r = 0; r < 4; ++r) {
            const size_t grow = (size_t)(bm + wm + i * 16 + h * 4 + r);
            float v0 = acc[i][0][r] + bias4.x;
            float v1 = acc[i][1][r] + bias4.y;
            float v2 = acc[i][2][r] + bias4.z;
            float v3 = acc[i][3][r] + bias4.w;
            if (EPI == 0) {
                bh4 o;
                o.x = __float2bfloat16(0.5f * v0 * (1.0f + erff(v0 * 0.70710678118654752f)));
                o.y = __float2bfloat16(0.5f * v1 * (1.0f + erff(v1 * 0.70710678118654752f)));
                o.z = __float2bfloat16(0.5f * v2 * (1.0f + erff(v2 * 0.70710678118654752f)));
                o.w = __float2bfloat16(0.5f * v3 * (1.0f + erff(v3 * 0.70710678118654752f)));
                *(bh4*)(outb + grow * N + colb) = o;
            } else {
                const float4 rs = *(const float4*)(resid + grow * N + colb);
                float4 o = {v0 + rs.x, v1 + rs.y, v2 + rs.z, v3 + rs.w};
                *(float4*)(outf + grow * N + colb) = o;
            }
        }
    }
}

extern "C" void kernel_launch(void* const* d_in, const int* in_sizes, int n_in,
                              void* d_out, int out_size, void* d_ws, size_t ws_size,
                              hipStream_t stream) {
    const float* x     = (const float*)d_in[0];
    const float* gamma = (const float*)d_in[1];
    const float* beta  = (const float*)d_in[2];
    const float* w1    = (const float*)d_in[3];
    const float* b1    = (const float*)d_in[4];
    const float* w2    = (const float*)d_in[5];
    const float* b2    = (const float*)d_in[6];
    float* out = (float*)d_out;

    const int M = in_sizes[0] / 1024;   // 16384

    char* ws = (char*)d_ws;
    __hip_bfloat16* hn  = (__hip_bfloat16*)ws;                          // 32 MiB
    __hip_bfloat16* h1  = (__hip_bfloat16*)(ws + (size_t)M * 2048);     // 32 MiB
    __hip_bfloat16* w1b = (__hip_bfloat16*)(ws + (size_t)M * 4096);     // 2 MiB
    __hip_bfloat16* w2b = (__hip_bfloat16*)(ws + (size_t)M * 4096 + 2097152);

    const int nln = M / 4;   // 4096 LN blocks + 1024 cvt blocks
    pre_kernel<<<nln + 1024, 256, 0, stream>>>(x, gamma, beta, w1, w2, hn, w1b, w2b, nln);
    // grid x = bm so id%8 = bm%8: same-bm blocks share an XCD (A-strip L2 reuse)
    gemm_kernel<0><<<dim3(M / 128, 8), 256, 0, stream>>>(hn, w1b, b1, nullptr, h1, nullptr);
    gemm_kernel<1><<<dim3(M / 128, 8), 256, 0, stream>>>(h1, w2b, b2, x, nullptr, out);
}